// Round 4
// baseline (880.998 us; speedup 1.0000x reference)
//
#include <hip/hip_runtime.h>

typedef unsigned short u16;
typedef unsigned int u32;
typedef __attribute__((ext_vector_type(8))) short short8;  // 8 bf16 (4 VGPRs)
typedef __attribute__((ext_vector_type(4))) float f32x4;

constexpr int NA = 50000, NB = 50000;
constexpr int EMB = 16, HID = 64;
constexpr int NE = 800000;
constexpr int NBKT = 782;   // buckets per relation, 64 dsts each (782*64=50048)
constexpr int CAPB = 1536;  // bucket capacity: mean 1024, sd 32 -> +16 sd

#define MFMA16(a, b, c) __builtin_amdgcn_mfma_f32_16x16x32_bf16(a, b, c, 0, 0, 0)

__device__ inline u16 f2bf(float f) {  // RNE f32->bf16
  u32 b = __float_as_uint(f);
  return (u16)((b + 0x7FFFu + ((b >> 16) & 1u)) >> 16);
}
__device__ inline float bfl(u32 u) { return __uint_as_float(u << 16); }
__device__ inline float bfh(u32 u) { return __uint_as_float(u & 0xFFFF0000u); }
__device__ inline float bfs(u16 u) { return __uint_as_float((u32)u << 16); }

// ---------------- K0: fold embedding tables through pre_W (f32 out) ----------------
__global__ void k_tables(const float* __restrict__ embA, const float* __restrict__ embB,
                         const float* __restrict__ preWA, const float* __restrict__ preWB,
                         float* __restrict__ T) {
  int id = blockIdx.x * 256 + threadIdx.x;  // 0..32767
  int type = id >> 14;
  int rem = id & 16383;
  int col = rem >> 8;
  int fdbin = rem & 255;
  int fd = fdbin >> 5;
  const float* emb = type ? embB : embA;
  const float* W = type ? preWB : preWA;
  const float* e = emb + fdbin * EMB;
  const float* w = W + (fd * EMB) * HID + col;
  float s = 0.f;
#pragma unroll
  for (int j = 0; j < EMB; ++j) s += e[j] * w[j * HID];
  T[id] = s;
}

// ---------------- K0b: pack all weights into MFMA B-fragment order (bf16) ----------
__global__ void k_prep(const float* __restrict__ Wr_ba, const float* __restrict__ Wr_aa,
                       const float* __restrict__ Wl_ba, const float* __restrict__ Wl_aa,
                       const float* __restrict__ Wl_ab, const float* __restrict__ Wr_ab,
                       const float* __restrict__ bl_ba, const float* __restrict__ bl_aa,
                       const float* __restrict__ projWA, const float* __restrict__ projWB,
                       const float* __restrict__ headWA, const float* __restrict__ headWB,
                       const float* __restrict__ bilW_ba, const float* __restrict__ bilW_aa,
                       const float* __restrict__ bilW_ab,
                       u16* __restrict__ frag, float* __restrict__ bhA) {
  int tid = blockIdx.x * 256 + threadIdx.x;
  if (tid >= 86 * 64) {
    int i = tid - 86 * 64;
    if (i < 64) bhA[i] = 0.5f * (bl_ba[i] + bl_aa[i]);
    return;
  }
  int f = tid >> 6, lane = tid & 63;
  int nidx = lane & 15, quad = lane >> 4;
  u16* dst = frag + (size_t)f * 512 + lane * 8;
#pragma unroll
  for (int j = 0; j < 8; ++j) {
    int kq = quad * 8 + j;
    float v;
    if (f < 24) {
      int s = f >> 2, nt = f & 3, k = s * 32 + kq, c = nt * 16 + nidx;
      v = (k < 64) ? 0.5f * (Wr_ba[k * 64 + c] + Wr_aa[k * 64 + c])
          : (k < 128) ? 0.5f * Wl_ba[(k - 64) * 64 + c]
                      : 0.5f * Wl_aa[(k - 128) * 64 + c];
    } else if (f < 28) {
      int g = f - 24, k = (g >> 1) * 32 + kq, c = (g & 1) * 16 + nidx;
      v = projWA[k * 32 + c];
    } else if (f < 44) {
      int c = (f - 28) * 16 + nidx;
      v = headWA[kq * 256 + c];
    } else if (f < 46) {
      int i2 = (f - 44) * 16 + nidx;
      v = bilW_ba[i2 * 32 + kq];
    } else if (f < 48) {
      int i2 = (f - 46) * 16 + nidx;
      v = bilW_aa[i2 * 32 + kq];
    } else if (f < 64) {
      int g = f - 48, s = g >> 2, nt = g & 3, k = s * 32 + kq, c = nt * 16 + nidx;
      v = (k < 64) ? Wr_ab[k * 64 + c] : Wl_ab[(k - 64) * 64 + c];
    } else if (f < 68) {
      int g = f - 64, k = (g >> 1) * 32 + kq, c = (g & 1) * 16 + nidx;
      v = projWB[k * 32 + c];
    } else if (f < 84) {
      int c = (f - 68) * 16 + nidx;
      v = headWB[kq * 256 + c];
    } else {
      int i2 = (f - 84) * 16 + nidx;
      v = bilW_ab[i2 * 32 + kq];
    }
    dst[j] = f2bf(v);
  }
}

// ---------------- K1: x0 = relu(bias + sum_fd T[fd][bin_fd][:]) -> bf16 ----------------
__global__ void __launch_bounds__(256) k_x0(const int* __restrict__ x,
                                            const float* __restrict__ T,
                                            const float* __restrict__ bias,
                                            u16* __restrict__ x0, int N) {
  extern __shared__ float Tl[];  // 16384 floats = 64KB
  const float4* Tg = (const float4*)T;
  float4* Ts = (float4*)Tl;
  for (int i = threadIdx.x; i < 4096; i += 256) {
    int col = i >> 6, b4 = i & 63;
    Ts[col * 64 + ((b4 + 2 * (col >> 4)) & 63)] = Tg[i];
  }
  __syncthreads();
  int t = threadIdx.x;
  int r = t >> 2, q = t & 3;
  int row = blockIdx.x * 64 + r;
  bool valid = row < N;
  int arow = valid ? row : (N - 1);
  const int4* xp = (const int4*)(x + arow * 8);
  int4 xa = xp[0], xb = xp[1];
  int bins[8] = {xa.x, xa.y, xa.z, xa.w, xb.x, xb.y, xb.z, xb.w};
  int c0 = q * 16;
  float acc[16];
#pragma unroll
  for (int j = 0; j < 16; ++j) acc[j] = bias[c0 + j];
#pragma unroll
  for (int fd = 0; fd < 8; ++fd) {
    int sb = ((fd * 32 + bins[fd]) + 8 * q) & 255;
#pragma unroll
    for (int j = 0; j < 16; ++j) acc[j] += Tl[(c0 + j) * 256 + sb];
  }
  if (valid) {
    u32 p[8];
#pragma unroll
    for (int j = 0; j < 8; ++j) {
      u16 lo = f2bf(fmaxf(acc[2 * j], 0.f));
      u16 hi = f2bf(fmaxf(acc[2 * j + 1], 0.f));
      p[j] = (u32)lo | ((u32)hi << 16);
    }
    u32* o = (u32*)(x0 + (size_t)row * 64 + c0);
    *(uint4*)o = *(uint4*)&p[0];
    *((uint4*)o + 1) = *(uint4*)&p[4];
  }
}

// ---------------- K2: coarse binning (64 dsts per bucket, append-style) -----------
// Entry = (src << 6) | (dst & 63). Appends cluster at the cursor frontier ->
// consecutive entries share cache lines (vs round-3 scatter: 64B writeback per 4B).
__global__ void k_bin_all(const int* __restrict__ ei_ab, const int* __restrict__ ei_ba,
                          const int* __restrict__ ei_aa, int* __restrict__ cur,
                          u32* __restrict__ buckets) {
  int e = blockIdx.x * 256 + threadIdx.x;  // grid exactly 3*NE
  int rel = e / NE;
  int le = e - rel * NE;
  const int* ei = rel == 0 ? ei_ab : (rel == 1 ? ei_ba : ei_aa);
  int src = ei[le];
  int dstn = ei[NE + le];
  int b = rel * NBKT + (dstn >> 6);
  int pos = atomicAdd(cur + b, 1);
  if (pos < CAPB) buckets[(size_t)b * CAPB + pos] = ((u32)src << 6) | (u32)(dstn & 63);
}

// ---------------- K3: per-bucket LDS counting-sort + gather-mean ----------------
// One block per bucket. lane=dim: each edge is one coalesced 128B bf16 row read.
__global__ void __launch_bounds__(256) k_meansort_all(
    const u32* __restrict__ buckets, const int* __restrict__ cur,
    const u16* __restrict__ x0A, const u16* __restrict__ x0B,
    u16* __restrict__ mab, u16* __restrict__ mba, u16* __restrict__ maa) {
  __shared__ u32 ebuf[CAPB];
  __shared__ u16 csr[CAPB];
  __shared__ int dcnt[64], doff[64], wcur[64];
  int blk = blockIdx.x;  // 0..3*NBKT-1
  int rel = blk / NBKT;
  int lb = blk - rel * NBKT;
  int t = threadIdx.x;
  const u16* x0 = (rel == 1) ? x0B : x0A;
  u16* out = rel == 0 ? mab : (rel == 1 ? mba : maa);
  int n = min(cur[blk], CAPB);
  const u32* bk = buckets + (size_t)blk * CAPB;
  if (t < 64) dcnt[t] = 0;
  __syncthreads();
  for (int i = t; i < n; i += 256) {
    u32 v = bk[i];
    ebuf[i] = v;
    atomicAdd(&dcnt[v & 63], 1);
  }
  __syncthreads();
  if (t == 0) {
    int s = 0;
#pragma unroll
    for (int d = 0; d < 64; ++d) {
      doff[d] = s;
      wcur[d] = s;
      s += dcnt[d];
    }
  }
  __syncthreads();
  for (int i = t; i < n; i += 256) {
    u32 v = ebuf[i];
    int p = atomicAdd(&wcur[v & 63], 1);
    csr[p] = (u16)(v >> 6);
  }
  __syncthreads();
  int lane = t & 63, w = t >> 6;
  int base = lb * 64;
  for (int dd = 0; dd < 16; ++dd) {
    int dloc = w * 16 + dd;
    int dstn = base + dloc;
    if (dstn >= 50000) break;  // wave-uniform
    int off = doff[dloc], deg = dcnt[dloc];
    float acc = 0.f;
    int i = 0;
    for (; i + 4 <= deg; i += 4) {
      int s0 = csr[off + i], s1 = csr[off + i + 1];
      int s2 = csr[off + i + 2], s3 = csr[off + i + 3];
      float v0 = bfs(x0[(size_t)s0 * 64 + lane]);
      float v1 = bfs(x0[(size_t)s1 * 64 + lane]);
      float v2 = bfs(x0[(size_t)s2 * 64 + lane]);
      float v3 = bfs(x0[(size_t)s3 * 64 + lane]);
      acc += v0 + v1 + v2 + v3;
    }
    for (; i < deg; ++i) acc += bfs(x0[(size_t)csr[off + i] * 64 + lane]);
    float inv = deg > 0 ? 1.f / (float)deg : 0.f;
    out[(size_t)dstn * 64 + lane] = f2bf(acc * inv);
  }
}

// ---------------- K4a: MFMA node chain A ----------------
// 4 waves/block, each wave owns 32 rows; no __syncthreads anywhere.
__global__ void __launch_bounds__(256) k_nodeA(
    const u16* __restrict__ x0, const u16* __restrict__ m1, const u16* __restrict__ m2,
    const u16* __restrict__ frag, const float* __restrict__ bhA,
    const float* __restrict__ projb, const float* __restrict__ headb,
    float* __restrict__ zout, float* __restrict__ flout,
    u16* __restrict__ zbf, u16* __restrict__ y1bf, u16* __restrict__ y2bf, int N) {
  __shared__ u16 lds[4][3584];  // per-wave: h 32x72, z 32x40
  int t = threadIdx.x, lane = t & 63, w = t >> 6;
  u16* hld = &lds[w][0];
  u16* zld = &lds[w][2304];
  int rows0 = blockIdx.x * 128 + w * 32;
  int nidx = lane & 15, quad = lane >> 4;
  size_t r0 = (size_t)min(rows0 + nidx, N - 1);
  size_t r1 = (size_t)min(rows0 + 16 + nidx, N - 1);

  // ---- stage 1: h = [x0|m1|m2] @ Wcat (K=192) ----
  f32x4 acc[2][4];
#pragma unroll
  for (int mt = 0; mt < 2; ++mt)
#pragma unroll
    for (int nt = 0; nt < 4; ++nt) acc[mt][nt] = {0.f, 0.f, 0.f, 0.f};
  const u16* mats[3] = {x0, m1, m2};
#pragma unroll
  for (int s = 0; s < 6; ++s) {
    const u16* src = mats[s >> 1];
    int koff = (s & 1) * 32 + quad * 8;
    short8 a0 = *(const short8*)(src + r0 * 64 + koff);
    short8 a1 = *(const short8*)(src + r1 * 64 + koff);
#pragma unroll
    for (int nt = 0; nt < 4; ++nt) {
      short8 b = *(const short8*)(frag + (size_t)(s * 4 + nt) * 512 + lane * 8);
      acc[0][nt] = MFMA16(a0, b, acc[0][nt]);
      acc[1][nt] = MFMA16(a1, b, acc[1][nt]);
    }
  }
#pragma unroll
  for (int mt = 0; mt < 2; ++mt)
#pragma unroll
    for (int nt = 0; nt < 4; ++nt) {
      int col = nt * 16 + nidx;
      float bb = bhA[col];
#pragma unroll
      for (int r2 = 0; r2 < 4; ++r2)
        hld[(mt * 16 + quad * 4 + r2) * 72 + col] = f2bf(acc[mt][nt][r2] + bb);
    }

  // ---- stage 2: z = relu(h @ projW + b) ----
  f32x4 zacc[2][2];
#pragma unroll
  for (int mt = 0; mt < 2; ++mt)
#pragma unroll
    for (int nt = 0; nt < 2; ++nt) zacc[mt][nt] = {0.f, 0.f, 0.f, 0.f};
#pragma unroll
  for (int s = 0; s < 2; ++s) {
    short8 a0 = *(const short8*)(hld + nidx * 72 + s * 32 + quad * 8);
    short8 a1 = *(const short8*)(hld + (16 + nidx) * 72 + s * 32 + quad * 8);
#pragma unroll
    for (int nt = 0; nt < 2; ++nt) {
      short8 b = *(const short8*)(frag + (size_t)(24 + s * 2 + nt) * 512 + lane * 8);
      zacc[0][nt] = MFMA16(a0, b, zacc[0][nt]);
      zacc[1][nt] = MFMA16(a1, b, zacc[1][nt]);
    }
  }
#pragma unroll
  for (int mt = 0; mt < 2; ++mt)
#pragma unroll
    for (int nt = 0; nt < 2; ++nt) {
      int col = nt * 16 + nidx;
      float pb = projb[col];
#pragma unroll
      for (int r2 = 0; r2 < 4; ++r2) {
        int rl = mt * 16 + quad * 4 + r2;
        float zv = fmaxf(zacc[mt][nt][r2] + pb, 0.f);
        zld[rl * 40 + col] = f2bf(zv);
        int grow = rows0 + rl;
        if (grow < N) zout[(size_t)grow * 32 + col] = zv;
      }
    }
  {  // coalesced bf16 z store (2 lanes per row)
    int rl = lane >> 1, hf = lane & 1;
    int grow = rows0 + rl;
    if (grow < N) {
      short8 v0 = *(const short8*)(zld + rl * 40 + hf * 16);
      short8 v1 = *(const short8*)(zld + rl * 40 + hf * 16 + 8);
      *(short8*)(zbf + (size_t)grow * 32 + hf * 16) = v0;
      *(short8*)(zbf + (size_t)grow * 32 + hf * 16 + 8) = v1;
    }
  }

  // ---- stage 3: y1/y2 = z @ bilW^T ----
  short8 az0 = *(const short8*)(zld + nidx * 40 + quad * 8);
  short8 az1 = *(const short8*)(zld + (16 + nidx) * 40 + quad * 8);
#pragma unroll
  for (int mat = 0; mat < 2; ++mat) {
    f32x4 ya[2][2];
#pragma unroll
    for (int mt = 0; mt < 2; ++mt)
#pragma unroll
      for (int nt = 0; nt < 2; ++nt) ya[mt][nt] = {0.f, 0.f, 0.f, 0.f};
#pragma unroll
    for (int nt = 0; nt < 2; ++nt) {
      short8 b = *(const short8*)(frag + (size_t)(44 + mat * 2 + nt) * 512 + lane * 8);
      ya[0][nt] = MFMA16(az0, b, ya[0][nt]);
      ya[1][nt] = MFMA16(az1, b, ya[1][nt]);
    }
#pragma unroll
    for (int mt = 0; mt < 2; ++mt)
#pragma unroll
      for (int nt = 0; nt < 2; ++nt)
#pragma unroll
        for (int r2 = 0; r2 < 4; ++r2)
          hld[(mt * 16 + quad * 4 + r2) * 40 + nt * 16 + nidx] = f2bf(ya[mt][nt][r2]);
    u16* yo = mat ? y2bf : y1bf;
    int rl = lane >> 1, hf = lane & 1;
    int grow = rows0 + rl;
    if (grow < N) {
      short8 v0 = *(const short8*)(hld + rl * 40 + hf * 16);
      short8 v1 = *(const short8*)(hld + rl * 40 + hf * 16 + 8);
      *(short8*)(yo + (size_t)grow * 32 + hf * 16) = v0;
      *(short8*)(yo + (size_t)grow * 32 + hf * 16 + 8) = v1;
    }
  }

  // ---- stage 4: fl = z @ headW + b (256 cols in 4 chunks) ----
  for (int chunk = 0; chunk < 4; ++chunk) {
    f32x4 fa[2][4];
#pragma unroll
    for (int mt = 0; mt < 2; ++mt)
#pragma unroll
      for (int nt = 0; nt < 4; ++nt) fa[mt][nt] = {0.f, 0.f, 0.f, 0.f};
#pragma unroll
    for (int nt = 0; nt < 4; ++nt) {
      short8 b = *(const short8*)(frag + (size_t)(28 + chunk * 4 + nt) * 512 + lane * 8);
      fa[0][nt] = MFMA16(az0, b, fa[0][nt]);
      fa[1][nt] = MFMA16(az1, b, fa[1][nt]);
    }
#pragma unroll
    for (int mt = 0; mt < 2; ++mt)
#pragma unroll
      for (int nt = 0; nt < 4; ++nt) {
        int col = chunk * 64 + nt * 16 + nidx;
        float hb = headb[col];
#pragma unroll
        for (int r2 = 0; r2 < 4; ++r2) {
          int grow = rows0 + mt * 16 + quad * 4 + r2;
          if (grow < N) flout[(size_t)grow * 256 + col] = fa[mt][nt][r2] + hb;
        }
      }
  }
}

// ---------------- K4b: MFMA node chain B ----------------
__global__ void __launch_bounds__(256) k_nodeB(
    const u16* __restrict__ x0, const u16* __restrict__ m1,
    const u16* __restrict__ frag, const float* __restrict__ blB,
    const float* __restrict__ projb, const float* __restrict__ headb,
    float* __restrict__ zout, float* __restrict__ flout,
    u16* __restrict__ zbf, u16* __restrict__ ybf, int N) {
  __shared__ u16 lds[4][3584];
  int t = threadIdx.x, lane = t & 63, w = t >> 6;
  u16* hld = &lds[w][0];
  u16* zld = &lds[w][2304];
  int rows0 = blockIdx.x * 128 + w * 32;
  int nidx = lane & 15, quad = lane >> 4;
  size_t r0 = (size_t)min(rows0 + nidx, N - 1);
  size_t r1 = (size_t)min(rows0 + 16 + nidx, N - 1);

  f32x4 acc[2][4];
#pragma unroll
  for (int mt = 0; mt < 2; ++mt)
#pragma unroll
    for (int nt = 0; nt < 4; ++nt) acc[mt][nt] = {0.f, 0.f, 0.f, 0.f};
#pragma unroll
  for (int s = 0; s < 4; ++s) {
    const u16* src = (s < 2) ? x0 : m1;
    int koff = (s & 1) * 32 + quad * 8;
    short8 a0 = *(const short8*)(src + r0 * 64 + koff);
    short8 a1 = *(const short8*)(src + r1 * 64 + koff);
#pragma unroll
    for (int nt = 0; nt < 4; ++nt) {
      short8 b = *(const short8*)(frag + (size_t)(48 + s * 4 + nt) * 512 + lane * 8);
      acc[0][nt] = MFMA16(a0, b, acc[0][nt]);
      acc[1][nt] = MFMA16(a1, b, acc[1][nt]);
    }
  }
#pragma unroll
  for (int mt = 0; mt < 2; ++mt)
#pragma unroll
    for (int nt = 0; nt < 4; ++nt) {
      int col = nt * 16 + nidx;
      float bb = blB[col];
#pragma unroll
      for (int r2 = 0; r2 < 4; ++r2)
        hld[(mt * 16 + quad * 4 + r2) * 72 + col] = f2bf(acc[mt][nt][r2] + bb);
    }

  f32x4 zacc[2][2];
#pragma unroll
  for (int mt = 0; mt < 2; ++mt)
#pragma unroll
    for (int nt = 0; nt < 2; ++nt) zacc[mt][nt] = {0.f, 0.f, 0.f, 0.f};
#pragma unroll
  for (int s = 0; s < 2; ++s) {
    short8 a0 = *(const short8*)(hld + nidx * 72 + s * 32 + quad * 8);
    short8 a1 = *(const short8*)(hld + (16 + nidx) * 72 + s * 32 + quad * 8);
#pragma unroll
    for (int nt = 0; nt < 2; ++nt) {
      short8 b = *(const short8*)(frag + (size_t)(64 + s * 2 + nt) * 512 + lane * 8);
      zacc[0][nt] = MFMA16(a0, b, zacc[0][nt]);
      zacc[1][nt] = MFMA16(a1, b, zacc[1][nt]);
    }
  }
#pragma unroll
  for (int mt = 0; mt < 2; ++mt)
#pragma unroll
    for (int nt = 0; nt < 2; ++nt) {
      int col = nt * 16 + nidx;
      float pb = projb[col];
#pragma unroll
      for (int r2 = 0; r2 < 4; ++r2) {
        int rl = mt * 16 + quad * 4 + r2;
        float zv = fmaxf(zacc[mt][nt][r2] + pb, 0.f);
        zld[rl * 40 + col] = f2bf(zv);
        int grow = rows0 + rl;
        if (grow < N) zout[(size_t)grow * 32 + col] = zv;
      }
    }
  {
    int rl = lane >> 1, hf = lane & 1;
    int grow = rows0 + rl;
    if (grow < N) {
      short8 v0 = *(const short8*)(zld + rl * 40 + hf * 16);
      short8 v1 = *(const short8*)(zld + rl * 40 + hf * 16 + 8);
      *(short8*)(zbf + (size_t)grow * 32 + hf * 16) = v0;
      *(short8*)(zbf + (size_t)grow * 32 + hf * 16 + 8) = v1;
    }
  }

  short8 az0 = *(const short8*)(zld + nidx * 40 + quad * 8);
  short8 az1 = *(const short8*)(zld + (16 + nidx) * 40 + quad * 8);
  {
    f32x4 ya[2][2];
#pragma unroll
    for (int mt = 0; mt < 2; ++mt)
#pragma unroll
      for (int nt = 0; nt < 2; ++nt) ya[mt][nt] = {0.f, 0.f, 0.f, 0.f};
#pragma unroll
    for (int nt = 0; nt < 2; ++nt) {
      short8 b = *(const short8*)(frag + (size_t)(84 + nt) * 512 + lane * 8);
      ya[0][nt] = MFMA16(az0, b, ya[0][nt]);
      ya[1][nt] = MFMA16(az1, b, ya[1][nt]);
    }
#pragma unroll
    for (int mt = 0; mt < 2; ++mt)
#pragma unroll
      for (int nt = 0; nt < 2; ++nt)
#pragma unroll
        for (int r2 = 0; r2 < 4; ++r2)
          hld[(mt * 16 + quad * 4 + r2) * 40 + nt * 16 + nidx] = f2bf(ya[mt][nt][r2]);
    int rl = lane >> 1, hf = lane & 1;
    int grow = rows0 + rl;
    if (grow < N) {
      short8 v0 = *(const short8*)(hld + rl * 40 + hf * 16);
      short8 v1 = *(const short8*)(hld + rl * 40 + hf * 16 + 8);
      *(short8*)(ybf + (size_t)grow * 32 + hf * 16) = v0;
      *(short8*)(ybf + (size_t)grow * 32 + hf * 16 + 8) = v1;
    }
  }

  for (int chunk = 0; chunk < 4; ++chunk) {
    f32x4 fa[2][4];
#pragma unroll
    for (int mt = 0; mt < 2; ++mt)
#pragma unroll
      for (int nt = 0; nt < 4; ++nt) fa[mt][nt] = {0.f, 0.f, 0.f, 0.f};
#pragma unroll
    for (int nt = 0; nt < 4; ++nt) {
      short8 b = *(const short8*)(frag + (size_t)(68 + chunk * 4 + nt) * 512 + lane * 8);
      fa[0][nt] = MFMA16(az0, b, fa[0][nt]);
      fa[1][nt] = MFMA16(az1, b, fa[1][nt]);
    }
#pragma unroll
    for (int mt = 0; mt < 2; ++mt)
#pragma unroll
      for (int nt = 0; nt < 4; ++nt) {
        int col = chunk * 64 + nt * 16 + nidx;
        float hb = headb[col];
#pragma unroll
        for (int r2 = 0; r2 < 4; ++r2) {
          int grow = rows0 + mt * 16 + quad * 4 + r2;
          if (grow < N) flout[(size_t)grow * 256 + col] = fa[mt][nt][r2] + hb;
        }
      }
  }
}

// ---------------- K5: fused bilinear edge scores (3 relations) ----------------
__global__ void k_bil_all(const int* __restrict__ ei_ab, const int* __restrict__ ei_ba,
                          const int* __restrict__ ei_aa,
                          const u16* __restrict__ zA, const u16* __restrict__ zB,
                          const u16* __restrict__ yab, const u16* __restrict__ yba,
                          const u16* __restrict__ yaa,
                          const float* __restrict__ b_ab, const float* __restrict__ b_ba,
                          const float* __restrict__ b_aa,
                          float* __restrict__ s_ab, float* __restrict__ s_ba,
                          float* __restrict__ s_aa) {
  int e = blockIdx.x * 256 + threadIdx.x;  // grid exactly 3*NE
  int rel = e / NE;
  int le = e - rel * NE;
  const int* ei = rel == 0 ? ei_ab : (rel == 1 ? ei_ba : ei_aa);
  const u16* zs = (rel == 1) ? zB : zA;
  const u16* yd = rel == 0 ? yab : (rel == 1 ? yba : yaa);
  const float* bb = rel == 0 ? b_ab : (rel == 1 ? b_ba : b_aa);
  float* so = rel == 0 ? s_ab : (rel == 1 ? s_ba : s_aa);
  int si = ei[le], di = ei[NE + le];
  const uint4* zp = (const uint4*)(zs + (size_t)si * 32);
  const uint4* yp = (const uint4*)(yd + (size_t)di * 32);
  float acc = 0.f;
#pragma unroll
  for (int i = 0; i < 4; ++i) {
    uint4 a = zp[i], c = yp[i];
    acc += bfl(a.x) * bfl(c.x) + bfh(a.x) * bfh(c.x);
    acc += bfl(a.y) * bfl(c.y) + bfh(a.y) * bfh(c.y);
    acc += bfl(a.z) * bfl(c.z) + bfh(a.z) * bfh(c.z);
    acc += bfl(a.w) * bfl(c.w) + bfh(a.w) * bfh(c.w);
  }
  so[le] = acc + bb[0];
}

extern "C" void kernel_launch(void* const* d_in, const int* in_sizes, int n_in,
                              void* d_out, int out_size, void* d_ws, size_t ws_size,
                              hipStream_t stream) {
  const int* xA = (const int*)d_in[0];
  const int* xB = (const int*)d_in[1];
  const int* ei_ab = (const int*)d_in[2];
  const int* ei_ba = (const int*)d_in[3];
  const int* ei_aa = (const int*)d_in[4];
  const float* embA = (const float*)d_in[5];
  const float* embB = (const float*)d_in[6];
  const float* preWA = (const float*)d_in[7];
  const float* prebA = (const float*)d_in[8];
  const float* preWB = (const float*)d_in[9];
  const float* prebB = (const float*)d_in[10];
  const float* Wl_ab = (const float*)d_in[11];
  const float* bl_ab = (const float*)d_in[12];
  const float* Wr_ab = (const float*)d_in[13];
  const float* Wl_ba = (const float*)d_in[14];
  const float* bl_ba = (const float*)d_in[15];
  const float* Wr_ba = (const float*)d_in[16];
  const float* Wl_aa = (const float*)d_in[17];
  const float* bl_aa = (const float*)d_in[18];
  const float* Wr_aa = (const float*)d_in[19];
  const float* projWA = (const float*)d_in[20];
  const float* projbA = (const float*)d_in[21];
  const float* projWB = (const float*)d_in[22];
  const float* projbB = (const float*)d_in[23];
  const float* headWA = (const float*)d_in[24];
  const float* headbA = (const float*)d_in[25];
  const float* headWB = (const float*)d_in[26];
  const float* headbB = (const float*)d_in[27];
  const float* bilW_ab = (const float*)d_in[28];
  const float* bilb_ab = (const float*)d_in[29];
  const float* bilW_ba = (const float*)d_in[30];
  const float* bilb_ba = (const float*)d_in[31];
  const float* bilW_aa = (const float*)d_in[32];
  const float* bilb_aa = (const float*)d_in[33];

  float* out = (float*)d_out;
  float* zA = out;                      // 50000*32
  float* zB = out + 1600000;            // 50000*32
  float* flA = out + 3200000;           // 50000*256
  float* flB = out + 16000000;          // 50000*256
  float* s_ab = out + 28800000;
  float* s_ba = out + 29600000;
  float* s_aa = out + 30400000;

  // workspace (byte offsets, all 16B-aligned)
  char* ws = (char*)d_ws;
  float* T = (float*)(ws + 0);            // 131072 B
  u16* x0Abf = (u16*)(ws + 131072);       // 6.4e6 B
  u16* x0Bbf = (u16*)(ws + 6531072);
  u16* mabbf = (u16*)(ws + 12931072);
  u16* mbabf = (u16*)(ws + 19331072);
  u16* maabf = (u16*)(ws + 25731072);
  u16* zAbf = (u16*)(ws + 32131072);      // 3.2e6 B
  u16* zBbf = (u16*)(ws + 35331072);
  u16* yabbf = (u16*)(ws + 38531072);
  u16* ybabf = (u16*)(ws + 41731072);
  u16* yaabf = (u16*)(ws + 44931072);
  int* cur = (int*)(ws + 48131072);       // 3*NBKT ints
  u16* frag = (u16*)(ws + 48731072);      // 88064 B
  float* bhA = (float*)(ws + 48819136);   // 256 B

  // coarse-bin buckets alias fl_A's d_out region (dead until k_nodeA runs):
  // 3 * 782 * 1536 * 4B = 14.4 MB << 51.2 MB available
  u32* buckets = (u32*)flA;

  hipMemsetAsync(cur, 0, 3 * NBKT * sizeof(int), stream);
  k_tables<<<128, 256, 0, stream>>>(embA, embB, preWA, preWB, T);
  k_prep<<<22, 256, 0, stream>>>(Wr_ba, Wr_aa, Wl_ba, Wl_aa, Wl_ab, Wr_ab,
                                 bl_ba, bl_aa, projWA, projWB, headWA, headWB,
                                 bilW_ba, bilW_aa, bilW_ab, frag, bhA);
  k_x0<<<(NA + 63) / 64, 256, 65536, stream>>>(xA, T, prebA, x0Abf, NA);
  k_x0<<<(NB + 63) / 64, 256, 65536, stream>>>(xB, T + 16384, prebB, x0Bbf, NB);

  k_bin_all<<<3 * NE / 256, 256, 0, stream>>>(ei_ab, ei_ba, ei_aa, cur, buckets);
  k_meansort_all<<<3 * NBKT, 256, 0, stream>>>(buckets, cur, x0Abf, x0Bbf,
                                               mabbf, mbabf, maabf);

  k_nodeA<<<(NA + 127) / 128, 256, 0, stream>>>(
      x0Abf, mbabf, maabf, frag, bhA, projbA, headbA,
      zA, flA, zAbf, ybabf, yaabf, NA);
  k_nodeB<<<(NB + 127) / 128, 256, 0, stream>>>(
      x0Bbf, mabbf, frag, bl_ab, projbB, headbB,
      zB, flB, zBbf, yabbf, NB);

  k_bil_all<<<3 * NE / 256, 256, 0, stream>>>(ei_ab, ei_ba, ei_aa, zAbf, zBbf,
                                              yabbf, ybabf, yaabf,
                                              bilb_ab, bilb_ba, bilb_aa,
                                              s_ab, s_ba, s_aa);
}

// Round 5
// 449.864 us; speedup vs baseline: 1.9584x; 1.9584x over previous
//
#include <hip/hip_runtime.h>

typedef unsigned short u16;
typedef unsigned int u32;
typedef __attribute__((ext_vector_type(8))) short short8;  // 8 bf16 (4 VGPRs)
typedef __attribute__((ext_vector_type(4))) float f32x4;

constexpr int NA = 50000, NB = 50000;
constexpr int EMB = 16, HID = 64;
constexpr int NE = 800000;
constexpr int NBKT = 782;   // buckets per relation, 64 dsts each (782*64=50048)
constexpr int CAPB = 1536;  // bucket capacity: mean 1024, sd 32 -> +16 sd
constexpr int EPB = 8192;   // edges per multisplit block (98 blocks/relation)
constexpr int BPR = (NE + EPB - 1) / EPB;  // 98

#define MFMA16(a, b, c) __builtin_amdgcn_mfma_f32_16x16x32_bf16(a, b, c, 0, 0, 0)

__device__ inline u16 f2bf(float f) {  // RNE f32->bf16
  u32 b = __float_as_uint(f);
  return (u16)((b + 0x7FFFu + ((b >> 16) & 1u)) >> 16);
}
__device__ inline float bfl(u32 u) { return __uint_as_float(u << 16); }
__device__ inline float bfh(u32 u) { return __uint_as_float(u & 0xFFFF0000u); }
__device__ inline float bfs(u16 u) { return __uint_as_float((u32)u << 16); }

// ---------------- K0: fold embedding tables through pre_W (f32 out) ----------------
__global__ void k_tables(const float* __restrict__ embA, const float* __restrict__ embB,
                         const float* __restrict__ preWA, const float* __restrict__ preWB,
                         float* __restrict__ T) {
  int id = blockIdx.x * 256 + threadIdx.x;  // 0..32767
  int type = id >> 14;
  int rem = id & 16383;
  int col = rem >> 8;
  int fdbin = rem & 255;
  int fd = fdbin >> 5;
  const float* emb = type ? embB : embA;
  const float* W = type ? preWB : preWA;
  const float* e = emb + fdbin * EMB;
  const float* w = W + (fd * EMB) * HID + col;
  float s = 0.f;
#pragma unroll
  for (int j = 0; j < EMB; ++j) s += e[j] * w[j * HID];
  T[id] = s;
}

// ---------------- K0b: pack all weights into MFMA B-fragment order (bf16) ----------
__global__ void k_prep(const float* __restrict__ Wr_ba, const float* __restrict__ Wr_aa,
                       const float* __restrict__ Wl_ba, const float* __restrict__ Wl_aa,
                       const float* __restrict__ Wl_ab, const float* __restrict__ Wr_ab,
                       const float* __restrict__ bl_ba, const float* __restrict__ bl_aa,
                       const float* __restrict__ projWA, const float* __restrict__ projWB,
                       const float* __restrict__ headWA, const float* __restrict__ headWB,
                       const float* __restrict__ bilW_ba, const float* __restrict__ bilW_aa,
                       const float* __restrict__ bilW_ab,
                       u16* __restrict__ frag, float* __restrict__ bhA) {
  int tid = blockIdx.x * 256 + threadIdx.x;
  if (tid >= 86 * 64) {
    int i = tid - 86 * 64;
    if (i < 64) bhA[i] = 0.5f * (bl_ba[i] + bl_aa[i]);
    return;
  }
  int f = tid >> 6, lane = tid & 63;
  int nidx = lane & 15, quad = lane >> 4;
  u16* dst = frag + (size_t)f * 512 + lane * 8;
#pragma unroll
  for (int j = 0; j < 8; ++j) {
    int kq = quad * 8 + j;
    float v;
    if (f < 24) {
      int s = f >> 2, nt = f & 3, k = s * 32 + kq, c = nt * 16 + nidx;
      v = (k < 64) ? 0.5f * (Wr_ba[k * 64 + c] + Wr_aa[k * 64 + c])
          : (k < 128) ? 0.5f * Wl_ba[(k - 64) * 64 + c]
                      : 0.5f * Wl_aa[(k - 128) * 64 + c];
    } else if (f < 28) {
      int g = f - 24, k = (g >> 1) * 32 + kq, c = (g & 1) * 16 + nidx;
      v = projWA[k * 32 + c];
    } else if (f < 44) {
      int c = (f - 28) * 16 + nidx;
      v = headWA[kq * 256 + c];
    } else if (f < 46) {
      int i2 = (f - 44) * 16 + nidx;
      v = bilW_ba[i2 * 32 + kq];
    } else if (f < 48) {
      int i2 = (f - 46) * 16 + nidx;
      v = bilW_aa[i2 * 32 + kq];
    } else if (f < 64) {
      int g = f - 48, s = g >> 2, nt = g & 3, k = s * 32 + kq, c = nt * 16 + nidx;
      v = (k < 64) ? Wr_ab[k * 64 + c] : Wl_ab[(k - 64) * 64 + c];
    } else if (f < 68) {
      int g = f - 64, k = (g >> 1) * 32 + kq, c = (g & 1) * 16 + nidx;
      v = projWB[k * 32 + c];
    } else if (f < 84) {
      int c = (f - 68) * 16 + nidx;
      v = headWB[kq * 256 + c];
    } else {
      int i2 = (f - 84) * 16 + nidx;
      v = bilW_ab[i2 * 32 + kq];
    }
    dst[j] = f2bf(v);
  }
}

// ---------------- K1: x0 = relu(bias + sum_fd T[fd][bin_fd][:]) -> bf16 ----------------
__global__ void __launch_bounds__(256) k_x0(const int* __restrict__ x,
                                            const float* __restrict__ T,
                                            const float* __restrict__ bias,
                                            u16* __restrict__ x0, int N) {
  extern __shared__ float Tl[];  // 16384 floats = 64KB
  const float4* Tg = (const float4*)T;
  float4* Ts = (float4*)Tl;
  for (int i = threadIdx.x; i < 4096; i += 256) {
    int col = i >> 6, b4 = i & 63;
    Ts[col * 64 + ((b4 + 2 * (col >> 4)) & 63)] = Tg[i];
  }
  __syncthreads();
  int t = threadIdx.x;
  int r = t >> 2, q = t & 3;
  int row = blockIdx.x * 64 + r;
  bool valid = row < N;
  int arow = valid ? row : (N - 1);
  const int4* xp = (const int4*)(x + arow * 8);
  int4 xa = xp[0], xb = xp[1];
  int bins[8] = {xa.x, xa.y, xa.z, xa.w, xb.x, xb.y, xb.z, xb.w};
  int c0 = q * 16;
  float acc[16];
#pragma unroll
  for (int j = 0; j < 16; ++j) acc[j] = bias[c0 + j];
#pragma unroll
  for (int fd = 0; fd < 8; ++fd) {
    int sb = ((fd * 32 + bins[fd]) + 8 * q) & 255;
#pragma unroll
    for (int j = 0; j < 16; ++j) acc[j] += Tl[(c0 + j) * 256 + sb];
  }
  if (valid) {
    u32 p[8];
#pragma unroll
    for (int j = 0; j < 8; ++j) {
      u16 lo = f2bf(fmaxf(acc[2 * j], 0.f));
      u16 hi = f2bf(fmaxf(acc[2 * j + 1], 0.f));
      p[j] = (u32)lo | ((u32)hi << 16);
    }
    u32* o = (u32*)(x0 + (size_t)row * 64 + c0);
    *(uint4*)o = *(uint4*)&p[0];
    *((uint4*)o + 1) = *(uint4*)&p[4];
  }
}

// ---------------- K2: per-block two-pass multi-split into coarse buckets ----------
// Each block owns EPB contiguous edges of one relation. LDS histogram ->
// one global atomicAdd per (block,bucket) reserves a contiguous run ->
// ranked writes fill the run. Kills per-edge global atomics AND line bounce.
__global__ void __launch_bounds__(256) k_multisplit(
    const int* __restrict__ ei_ab, const int* __restrict__ ei_ba,
    const int* __restrict__ ei_aa, int* __restrict__ gcur,
    u32* __restrict__ buckets) {
  __shared__ int hist[NBKT];
  __shared__ int wcur[NBKT];  // becomes running global-write cursor per bucket
  int blk = blockIdx.x;  // 0..3*BPR-1
  int rel = blk / BPR;
  int lb = blk - rel * BPR;
  int t = threadIdx.x;
  const int* ei = rel == 0 ? ei_ab : (rel == 1 ? ei_ba : ei_aa);
  int e0 = lb * EPB;
  int n = min(EPB, NE - e0);
  for (int i = t; i < NBKT; i += 256) hist[i] = 0;
  __syncthreads();
  // pass 1: block-local histogram of coarse bucket (dst>>6)
  for (int i = t; i < n; i += 256) {
    int dstn = ei[NE + e0 + i];
    atomicAdd(&hist[dstn >> 6], 1);
  }
  __syncthreads();
  // reserve: one global atomic per present bucket
  for (int i = t; i < NBKT; i += 256) {
    int c = hist[i];
    wcur[i] = (c > 0) ? atomicAdd(&gcur[rel * NBKT + i], c) : 0;
  }
  __syncthreads();
  // pass 2: ranked write into the reserved runs (edge reads are L2-hot)
  for (int i = t; i < n; i += 256) {
    int src = ei[e0 + i];
    int dstn = ei[NE + e0 + i];
    int b = dstn >> 6;
    int pos = atomicAdd(&wcur[b], 1);
    if (pos < CAPB)
      buckets[(size_t)(rel * NBKT + b) * CAPB + pos] =
          ((u32)src << 6) | (u32)(dstn & 63);
  }
}

// ---------------- K3: per-bucket LDS counting-sort + gather-mean ----------------
// One block per bucket. lane=dim: each edge is one coalesced 128B bf16 row read.
__global__ void __launch_bounds__(256) k_meansort_all(
    const u32* __restrict__ buckets, const int* __restrict__ cur,
    const u16* __restrict__ x0A, const u16* __restrict__ x0B,
    u16* __restrict__ mab, u16* __restrict__ mba, u16* __restrict__ maa) {
  __shared__ u32 ebuf[CAPB];
  __shared__ u16 csr[CAPB];
  __shared__ int dcnt[64], doff[64], wcur[64];
  int blk = blockIdx.x;  // 0..3*NBKT-1
  int rel = blk / NBKT;
  int lb = blk - rel * NBKT;
  int t = threadIdx.x;
  const u16* x0 = (rel == 1) ? x0B : x0A;
  u16* out = rel == 0 ? mab : (rel == 1 ? mba : maa);
  int n = min(cur[blk], CAPB);
  const u32* bk = buckets + (size_t)blk * CAPB;
  if (t < 64) dcnt[t] = 0;
  __syncthreads();
  for (int i = t; i < n; i += 256) {
    u32 v = bk[i];
    ebuf[i] = v;
    atomicAdd(&dcnt[v & 63], 1);
  }
  __syncthreads();
  if (t == 0) {
    int s = 0;
#pragma unroll
    for (int d = 0; d < 64; ++d) {
      doff[d] = s;
      wcur[d] = s;
      s += dcnt[d];
    }
  }
  __syncthreads();
  for (int i = t; i < n; i += 256) {
    u32 v = ebuf[i];
    int p = atomicAdd(&wcur[v & 63], 1);
    csr[p] = (u16)(v >> 6);
  }
  __syncthreads();
  int lane = t & 63, w = t >> 6;
  int base = lb * 64;
  for (int dd = 0; dd < 16; ++dd) {
    int dloc = w * 16 + dd;
    int dstn = base + dloc;
    if (dstn >= 50000) break;  // wave-uniform
    int off = doff[dloc], deg = dcnt[dloc];
    float acc = 0.f;
    int i = 0;
    for (; i + 4 <= deg; i += 4) {
      int s0 = csr[off + i], s1 = csr[off + i + 1];
      int s2 = csr[off + i + 2], s3 = csr[off + i + 3];
      float v0 = bfs(x0[(size_t)s0 * 64 + lane]);
      float v1 = bfs(x0[(size_t)s1 * 64 + lane]);
      float v2 = bfs(x0[(size_t)s2 * 64 + lane]);
      float v3 = bfs(x0[(size_t)s3 * 64 + lane]);
      acc += v0 + v1 + v2 + v3;
    }
    for (; i < deg; ++i) acc += bfs(x0[(size_t)csr[off + i] * 64 + lane]);
    float inv = deg > 0 ? 1.f / (float)deg : 0.f;
    out[(size_t)dstn * 64 + lane] = f2bf(acc * inv);
  }
}

// ---------------- K4a: MFMA node chain A ----------------
// 4 waves/block, each wave owns 32 rows; no __syncthreads anywhere.
__global__ void __launch_bounds__(256) k_nodeA(
    const u16* __restrict__ x0, const u16* __restrict__ m1, const u16* __restrict__ m2,
    const u16* __restrict__ frag, const float* __restrict__ bhA,
    const float* __restrict__ projb, const float* __restrict__ headb,
    float* __restrict__ zout, float* __restrict__ flout,
    u16* __restrict__ zbf, u16* __restrict__ y1bf, u16* __restrict__ y2bf, int N) {
  __shared__ u16 lds[4][3584];  // per-wave: h 32x72, z 32x40
  int t = threadIdx.x, lane = t & 63, w = t >> 6;
  u16* hld = &lds[w][0];
  u16* zld = &lds[w][2304];
  int rows0 = blockIdx.x * 128 + w * 32;
  int nidx = lane & 15, quad = lane >> 4;
  size_t r0 = (size_t)min(rows0 + nidx, N - 1);
  size_t r1 = (size_t)min(rows0 + 16 + nidx, N - 1);

  // ---- stage 1: h = [x0|m1|m2] @ Wcat (K=192) ----
  f32x4 acc[2][4];
#pragma unroll
  for (int mt = 0; mt < 2; ++mt)
#pragma unroll
    for (int nt = 0; nt < 4; ++nt) acc[mt][nt] = {0.f, 0.f, 0.f, 0.f};
  const u16* mats[3] = {x0, m1, m2};
#pragma unroll
  for (int s = 0; s < 6; ++s) {
    const u16* src = mats[s >> 1];
    int koff = (s & 1) * 32 + quad * 8;
    short8 a0 = *(const short8*)(src + r0 * 64 + koff);
    short8 a1 = *(const short8*)(src + r1 * 64 + koff);
#pragma unroll
    for (int nt = 0; nt < 4; ++nt) {
      short8 b = *(const short8*)(frag + (size_t)(s * 4 + nt) * 512 + lane * 8);
      acc[0][nt] = MFMA16(a0, b, acc[0][nt]);
      acc[1][nt] = MFMA16(a1, b, acc[1][nt]);
    }
  }
#pragma unroll
  for (int mt = 0; mt < 2; ++mt)
#pragma unroll
    for (int nt = 0; nt < 4; ++nt) {
      int col = nt * 16 + nidx;
      float bb = bhA[col];
#pragma unroll
      for (int r2 = 0; r2 < 4; ++r2)
        hld[(mt * 16 + quad * 4 + r2) * 72 + col] = f2bf(acc[mt][nt][r2] + bb);
    }

  // ---- stage 2: z = relu(h @ projW + b) ----
  f32x4 zacc[2][2];
#pragma unroll
  for (int mt = 0; mt < 2; ++mt)
#pragma unroll
    for (int nt = 0; nt < 2; ++nt) zacc[mt][nt] = {0.f, 0.f, 0.f, 0.f};
#pragma unroll
  for (int s = 0; s < 2; ++s) {
    short8 a0 = *(const short8*)(hld + nidx * 72 + s * 32 + quad * 8);
    short8 a1 = *(const short8*)(hld + (16 + nidx) * 72 + s * 32 + quad * 8);
#pragma unroll
    for (int nt = 0; nt < 2; ++nt) {
      short8 b = *(const short8*)(frag + (size_t)(24 + s * 2 + nt) * 512 + lane * 8);
      zacc[0][nt] = MFMA16(a0, b, zacc[0][nt]);
      zacc[1][nt] = MFMA16(a1, b, zacc[1][nt]);
    }
  }
#pragma unroll
  for (int mt = 0; mt < 2; ++mt)
#pragma unroll
    for (int nt = 0; nt < 2; ++nt) {
      int col = nt * 16 + nidx;
      float pb = projb[col];
#pragma unroll
      for (int r2 = 0; r2 < 4; ++r2) {
        int rl = mt * 16 + quad * 4 + r2;
        float zv = fmaxf(zacc[mt][nt][r2] + pb, 0.f);
        zld[rl * 40 + col] = f2bf(zv);
        int grow = rows0 + rl;
        if (grow < N) zout[(size_t)grow * 32 + col] = zv;
      }
    }
  {  // coalesced bf16 z store (2 lanes per row)
    int rl = lane >> 1, hf = lane & 1;
    int grow = rows0 + rl;
    if (grow < N) {
      short8 v0 = *(const short8*)(zld + rl * 40 + hf * 16);
      short8 v1 = *(const short8*)(zld + rl * 40 + hf * 16 + 8);
      *(short8*)(zbf + (size_t)grow * 32 + hf * 16) = v0;
      *(short8*)(zbf + (size_t)grow * 32 + hf * 16 + 8) = v1;
    }
  }

  // ---- stage 3: y1/y2 = z @ bilW^T ----
  short8 az0 = *(const short8*)(zld + nidx * 40 + quad * 8);
  short8 az1 = *(const short8*)(zld + (16 + nidx) * 40 + quad * 8);
#pragma unroll
  for (int mat = 0; mat < 2; ++mat) {
    f32x4 ya[2][2];
#pragma unroll
    for (int mt = 0; mt < 2; ++mt)
#pragma unroll
      for (int nt = 0; nt < 2; ++nt) ya[mt][nt] = {0.f, 0.f, 0.f, 0.f};
#pragma unroll
    for (int nt = 0; nt < 2; ++nt) {
      short8 b = *(const short8*)(frag + (size_t)(44 + mat * 2 + nt) * 512 + lane * 8);
      ya[0][nt] = MFMA16(az0, b, ya[0][nt]);
      ya[1][nt] = MFMA16(az1, b, ya[1][nt]);
    }
#pragma unroll
    for (int mt = 0; mt < 2; ++mt)
#pragma unroll
      for (int nt = 0; nt < 2; ++nt)
#pragma unroll
        for (int r2 = 0; r2 < 4; ++r2)
          hld[(mt * 16 + quad * 4 + r2) * 40 + nt * 16 + nidx] = f2bf(ya[mt][nt][r2]);
    u16* yo = mat ? y2bf : y1bf;
    int rl = lane >> 1, hf = lane & 1;
    int grow = rows0 + rl;
    if (grow < N) {
      short8 v0 = *(const short8*)(hld + rl * 40 + hf * 16);
      short8 v1 = *(const short8*)(hld + rl * 40 + hf * 16 + 8);
      *(short8*)(yo + (size_t)grow * 32 + hf * 16) = v0;
      *(short8*)(yo + (size_t)grow * 32 + hf * 16 + 8) = v1;
    }
  }

  // ---- stage 4: fl = z @ headW + b (256 cols in 4 chunks) ----
  for (int chunk = 0; chunk < 4; ++chunk) {
    f32x4 fa[2][4];
#pragma unroll
    for (int mt = 0; mt < 2; ++mt)
#pragma unroll
      for (int nt = 0; nt < 4; ++nt) fa[mt][nt] = {0.f, 0.f, 0.f, 0.f};
#pragma unroll
    for (int nt = 0; nt < 4; ++nt) {
      short8 b = *(const short8*)(frag + (size_t)(28 + chunk * 4 + nt) * 512 + lane * 8);
      fa[0][nt] = MFMA16(az0, b, fa[0][nt]);
      fa[1][nt] = MFMA16(az1, b, fa[1][nt]);
    }
#pragma unroll
    for (int mt = 0; mt < 2; ++mt)
#pragma unroll
      for (int nt = 0; nt < 4; ++nt) {
        int col = chunk * 64 + nt * 16 + nidx;
        float hb = headb[col];
#pragma unroll
        for (int r2 = 0; r2 < 4; ++r2) {
          int grow = rows0 + mt * 16 + quad * 4 + r2;
          if (grow < N) flout[(size_t)grow * 256 + col] = fa[mt][nt][r2] + hb;
        }
      }
  }
}

// ---------------- K4b: MFMA node chain B ----------------
__global__ void __launch_bounds__(256) k_nodeB(
    const u16* __restrict__ x0, const u16* __restrict__ m1,
    const u16* __restrict__ frag, const float* __restrict__ blB,
    const float* __restrict__ projb, const float* __restrict__ headb,
    float* __restrict__ zout, float* __restrict__ flout,
    u16* __restrict__ zbf, u16* __restrict__ ybf, int N) {
  __shared__ u16 lds[4][3584];
  int t = threadIdx.x, lane = t & 63, w = t >> 6;
  u16* hld = &lds[w][0];
  u16* zld = &lds[w][2304];
  int rows0 = blockIdx.x * 128 + w * 32;
  int nidx = lane & 15, quad = lane >> 4;
  size_t r0 = (size_t)min(rows0 + nidx, N - 1);
  size_t r1 = (size_t)min(rows0 + 16 + nidx, N - 1);

  f32x4 acc[2][4];
#pragma unroll
  for (int mt = 0; mt < 2; ++mt)
#pragma unroll
    for (int nt = 0; nt < 4; ++nt) acc[mt][nt] = {0.f, 0.f, 0.f, 0.f};
#pragma unroll
  for (int s = 0; s < 4; ++s) {
    const u16* src = (s < 2) ? x0 : m1;
    int koff = (s & 1) * 32 + quad * 8;
    short8 a0 = *(const short8*)(src + r0 * 64 + koff);
    short8 a1 = *(const short8*)(src + r1 * 64 + koff);
#pragma unroll
    for (int nt = 0; nt < 4; ++nt) {
      short8 b = *(const short8*)(frag + (size_t)(48 + s * 4 + nt) * 512 + lane * 8);
      acc[0][nt] = MFMA16(a0, b, acc[0][nt]);
      acc[1][nt] = MFMA16(a1, b, acc[1][nt]);
    }
  }
#pragma unroll
  for (int mt = 0; mt < 2; ++mt)
#pragma unroll
    for (int nt = 0; nt < 4; ++nt) {
      int col = nt * 16 + nidx;
      float bb = blB[col];
#pragma unroll
      for (int r2 = 0; r2 < 4; ++r2)
        hld[(mt * 16 + quad * 4 + r2) * 72 + col] = f2bf(acc[mt][nt][r2] + bb);
    }

  f32x4 zacc[2][2];
#pragma unroll
  for (int mt = 0; mt < 2; ++mt)
#pragma unroll
    for (int nt = 0; nt < 2; ++nt) zacc[mt][nt] = {0.f, 0.f, 0.f, 0.f};
#pragma unroll
  for (int s = 0; s < 2; ++s) {
    short8 a0 = *(const short8*)(hld + nidx * 72 + s * 32 + quad * 8);
    short8 a1 = *(const short8*)(hld + (16 + nidx) * 72 + s * 32 + quad * 8);
#pragma unroll
    for (int nt = 0; nt < 2; ++nt) {
      short8 b = *(const short8*)(frag + (size_t)(64 + s * 2 + nt) * 512 + lane * 8);
      zacc[0][nt] = MFMA16(a0, b, zacc[0][nt]);
      zacc[1][nt] = MFMA16(a1, b, zacc[1][nt]);
    }
  }
#pragma unroll
  for (int mt = 0; mt < 2; ++mt)
#pragma unroll
    for (int nt = 0; nt < 2; ++nt) {
      int col = nt * 16 + nidx;
      float pb = projb[col];
#pragma unroll
      for (int r2 = 0; r2 < 4; ++r2) {
        int rl = mt * 16 + quad * 4 + r2;
        float zv = fmaxf(zacc[mt][nt][r2] + pb, 0.f);
        zld[rl * 40 + col] = f2bf(zv);
        int grow = rows0 + rl;
        if (grow < N) zout[(size_t)grow * 32 + col] = zv;
      }
    }
  {
    int rl = lane >> 1, hf = lane & 1;
    int grow = rows0 + rl;
    if (grow < N) {
      short8 v0 = *(const short8*)(zld + rl * 40 + hf * 16);
      short8 v1 = *(const short8*)(zld + rl * 40 + hf * 16 + 8);
      *(short8*)(zbf + (size_t)grow * 32 + hf * 16) = v0;
      *(short8*)(zbf + (size_t)grow * 32 + hf * 16 + 8) = v1;
    }
  }

  short8 az0 = *(const short8*)(zld + nidx * 40 + quad * 8);
  short8 az1 = *(const short8*)(zld + (16 + nidx) * 40 + quad * 8);
  {
    f32x4 ya[2][2];
#pragma unroll
    for (int mt = 0; mt < 2; ++mt)
#pragma unroll
      for (int nt = 0; nt < 2; ++nt) ya[mt][nt] = {0.f, 0.f, 0.f, 0.f};
#pragma unroll
    for (int nt = 0; nt < 2; ++nt) {
      short8 b = *(const short8*)(frag + (size_t)(84 + nt) * 512 + lane * 8);
      ya[0][nt] = MFMA16(az0, b, ya[0][nt]);
      ya[1][nt] = MFMA16(az1, b, ya[1][nt]);
    }
#pragma unroll
    for (int mt = 0; mt < 2; ++mt)
#pragma unroll
      for (int nt = 0; nt < 2; ++nt)
#pragma unroll
        for (int r2 = 0; r2 < 4; ++r2)
          hld[(mt * 16 + quad * 4 + r2) * 40 + nt * 16 + nidx] = f2bf(ya[mt][nt][r2]);
    int rl = lane >> 1, hf = lane & 1;
    int grow = rows0 + rl;
    if (grow < N) {
      short8 v0 = *(const short8*)(hld + rl * 40 + hf * 16);
      short8 v1 = *(const short8*)(hld + rl * 40 + hf * 16 + 8);
      *(short8*)(ybf + (size_t)grow * 32 + hf * 16) = v0;
      *(short8*)(ybf + (size_t)grow * 32 + hf * 16 + 8) = v1;
    }
  }

  for (int chunk = 0; chunk < 4; ++chunk) {
    f32x4 fa[2][4];
#pragma unroll
    for (int mt = 0; mt < 2; ++mt)
#pragma unroll
      for (int nt = 0; nt < 4; ++nt) fa[mt][nt] = {0.f, 0.f, 0.f, 0.f};
#pragma unroll
    for (int nt = 0; nt < 4; ++nt) {
      short8 b = *(const short8*)(frag + (size_t)(68 + chunk * 4 + nt) * 512 + lane * 8);
      fa[0][nt] = MFMA16(az0, b, fa[0][nt]);
      fa[1][nt] = MFMA16(az1, b, fa[1][nt]);
    }
#pragma unroll
    for (int mt = 0; mt < 2; ++mt)
#pragma unroll
      for (int nt = 0; nt < 4; ++nt) {
        int col = chunk * 64 + nt * 16 + nidx;
        float hb = headb[col];
#pragma unroll
        for (int r2 = 0; r2 < 4; ++r2) {
          int grow = rows0 + mt * 16 + quad * 4 + r2;
          if (grow < N) flout[(size_t)grow * 256 + col] = fa[mt][nt][r2] + hb;
        }
      }
  }
}

// ---------------- K5: fused bilinear edge scores (3 relations) ----------------
__global__ void k_bil_all(const int* __restrict__ ei_ab, const int* __restrict__ ei_ba,
                          const int* __restrict__ ei_aa,
                          const u16* __restrict__ zA, const u16* __restrict__ zB,
                          const u16* __restrict__ yab, const u16* __restrict__ yba,
                          const u16* __restrict__ yaa,
                          const float* __restrict__ b_ab, const float* __restrict__ b_ba,
                          const float* __restrict__ b_aa,
                          float* __restrict__ s_ab, float* __restrict__ s_ba,
                          float* __restrict__ s_aa) {
  int e = blockIdx.x * 256 + threadIdx.x;  // grid exactly 3*NE
  int rel = e / NE;
  int le = e - rel * NE;
  const int* ei = rel == 0 ? ei_ab : (rel == 1 ? ei_ba : ei_aa);
  const u16* zs = (rel == 1) ? zB : zA;
  const u16* yd = rel == 0 ? yab : (rel == 1 ? yba : yaa);
  const float* bb = rel == 0 ? b_ab : (rel == 1 ? b_ba : b_aa);
  float* so = rel == 0 ? s_ab : (rel == 1 ? s_ba : s_aa);
  int si = ei[le], di = ei[NE + le];
  const uint4* zp = (const uint4*)(zs + (size_t)si * 32);
  const uint4* yp = (const uint4*)(yd + (size_t)di * 32);
  float acc = 0.f;
#pragma unroll
  for (int i = 0; i < 4; ++i) {
    uint4 a = zp[i], c = yp[i];
    acc += bfl(a.x) * bfl(c.x) + bfh(a.x) * bfh(c.x);
    acc += bfl(a.y) * bfl(c.y) + bfh(a.y) * bfh(c.y);
    acc += bfl(a.z) * bfl(c.z) + bfh(a.z) * bfh(c.z);
    acc += bfl(a.w) * bfl(c.w) + bfh(a.w) * bfh(c.w);
  }
  so[le] = acc + bb[0];
}

extern "C" void kernel_launch(void* const* d_in, const int* in_sizes, int n_in,
                              void* d_out, int out_size, void* d_ws, size_t ws_size,
                              hipStream_t stream) {
  const int* xA = (const int*)d_in[0];
  const int* xB = (const int*)d_in[1];
  const int* ei_ab = (const int*)d_in[2];
  const int* ei_ba = (const int*)d_in[3];
  const int* ei_aa = (const int*)d_in[4];
  const float* embA = (const float*)d_in[5];
  const float* embB = (const float*)d_in[6];
  const float* preWA = (const float*)d_in[7];
  const float* prebA = (const float*)d_in[8];
  const float* preWB = (const float*)d_in[9];
  const float* prebB = (const float*)d_in[10];
  const float* Wl_ab = (const float*)d_in[11];
  const float* bl_ab = (const float*)d_in[12];
  const float* Wr_ab = (const float*)d_in[13];
  const float* Wl_ba = (const float*)d_in[14];
  const float* bl_ba = (const float*)d_in[15];
  const float* Wr_ba = (const float*)d_in[16];
  const float* Wl_aa = (const float*)d_in[17];
  const float* bl_aa = (const float*)d_in[18];
  const float* Wr_aa = (const float*)d_in[19];
  const float* projWA = (const float*)d_in[20];
  const float* projbA = (const float*)d_in[21];
  const float* projWB = (const float*)d_in[22];
  const float* projbB = (const float*)d_in[23];
  const float* headWA = (const float*)d_in[24];
  const float* headbA = (const float*)d_in[25];
  const float* headWB = (const float*)d_in[26];
  const float* headbB = (const float*)d_in[27];
  const float* bilW_ab = (const float*)d_in[28];
  const float* bilb_ab = (const float*)d_in[29];
  const float* bilW_ba = (const float*)d_in[30];
  const float* bilb_ba = (const float*)d_in[31];
  const float* bilW_aa = (const float*)d_in[32];
  const float* bilb_aa = (const float*)d_in[33];

  float* out = (float*)d_out;
  float* zA = out;                      // 50000*32
  float* zB = out + 1600000;            // 50000*32
  float* flA = out + 3200000;           // 50000*256
  float* flB = out + 16000000;          // 50000*256
  float* s_ab = out + 28800000;
  float* s_ba = out + 29600000;
  float* s_aa = out + 30400000;

  // workspace (byte offsets, all 16B-aligned)
  char* ws = (char*)d_ws;
  float* T = (float*)(ws + 0);            // 131072 B
  u16* x0Abf = (u16*)(ws + 131072);       // 6.4e6 B
  u16* x0Bbf = (u16*)(ws + 6531072);
  u16* mabbf = (u16*)(ws + 12931072);
  u16* mbabf = (u16*)(ws + 19331072);
  u16* maabf = (u16*)(ws + 25731072);
  u16* zAbf = (u16*)(ws + 32131072);      // 3.2e6 B
  u16* zBbf = (u16*)(ws + 35331072);
  u16* yabbf = (u16*)(ws + 38531072);
  u16* ybabf = (u16*)(ws + 41731072);
  u16* yaabf = (u16*)(ws + 44931072);
  int* cur = (int*)(ws + 48131072);       // 3*NBKT ints
  u16* frag = (u16*)(ws + 48731072);      // 88064 B
  float* bhA = (float*)(ws + 48819136);   // 256 B

  // coarse-bin buckets alias fl_A's d_out region (dead until k_nodeA runs):
  // 3 * 782 * 1536 * 4B = 14.4 MB << 51.2 MB available
  u32* buckets = (u32*)flA;

  hipMemsetAsync(cur, 0, 3 * NBKT * sizeof(int), stream);
  k_tables<<<128, 256, 0, stream>>>(embA, embB, preWA, preWB, T);
  k_prep<<<22, 256, 0, stream>>>(Wr_ba, Wr_aa, Wl_ba, Wl_aa, Wl_ab, Wr_ab,
                                 bl_ba, bl_aa, projWA, projWB, headWA, headWB,
                                 bilW_ba, bilW_aa, bilW_ab, frag, bhA);
  k_x0<<<(NA + 63) / 64, 256, 65536, stream>>>(xA, T, prebA, x0Abf, NA);
  k_x0<<<(NB + 63) / 64, 256, 65536, stream>>>(xB, T + 16384, prebB, x0Bbf, NB);

  k_multisplit<<<3 * BPR, 256, 0, stream>>>(ei_ab, ei_ba, ei_aa, cur, buckets);
  k_meansort_all<<<3 * NBKT, 256, 0, stream>>>(buckets, cur, x0Abf, x0Bbf,
                                               mabbf, mbabf, maabf);

  k_nodeA<<<(NA + 127) / 128, 256, 0, stream>>>(
      x0Abf, mbabf, maabf, frag, bhA, projbA, headbA,
      zA, flA, zAbf, ybabf, yaabf, NA);
  k_nodeB<<<(NB + 127) / 128, 256, 0, stream>>>(
      x0Bbf, mabbf, frag, bl_ab, projbB, headbB,
      zB, flB, zBbf, yabbf, NB);

  k_bil_all<<<3 * NE / 256, 256, 0, stream>>>(ei_ab, ei_ba, ei_aa, zAbf, zBbf,
                                              yabbf, ybabf, yaabf,
                                              bilb_ab, bilb_ba, bilb_aa,
                                              s_ab, s_ba, s_aa);
}